// Round 1
// baseline (11658.289 us; speedup 1.0000x reference)
//
#include <hip/hip_runtime.h>
#include <hip/hip_bf16.h>

#define B_    64
#define C_    3
#define H_    224
#define W_    224
#define P_    16
#define GH_   14
#define NP_   196
#define PD_   768
#define HEADS_ 8
#define VDIM_ 128
#define DIM_  1024
#define DEPTH_ 6
#define NC_   1000
#define EPS_  1e-5f
#define SCALE_ 0.08838834764831845f   // 128^-0.5
#define ROWS_ (B_*NP_)                 // 12544

// ---------------- block-wide twin reduction (sum of a, sum of b) -------------
__device__ inline void block_reduce_2(float& a, float& b) {
    __shared__ float sa[4], sb[4];
    #pragma unroll
    for (int o = 32; o > 0; o >>= 1) {
        a += __shfl_down(a, o);
        b += __shfl_down(b, o);
    }
    int lane = threadIdx.x & 63, wid = threadIdx.x >> 6;
    if (lane == 0) { sa[wid] = a; sb[wid] = b; }
    __syncthreads();
    a = sa[0] + sa[1] + sa[2] + sa[3];
    b = sb[0] + sb[1] + sb[2] + sb[3];
    __syncthreads();
}

// ---------------- patchify + LayerNorm over PD=768 ---------------------------
// out[b, n, (p1*16+p2)*3 + c] = LN(image[b, c, gh*16+p1, gw*16+p2])
__global__ void patchify_ln(const float* __restrict__ img,
                            const float* __restrict__ g,
                            const float* __restrict__ beta,
                            float* __restrict__ out) {
    int bn = blockIdx.x;              // 0..12543
    int b = bn / NP_, n = bn % NP_;
    int gh = n / GH_, gw = n % GH_;
    int t = threadIdx.x;              // == pixel index 0..255
    int p1 = t >> 4, p2 = t & 15;
    int row = gh * P_ + p1, col = gw * P_ + p2;
    const float* ip = img + (size_t)b * C_ * H_ * W_ + (size_t)row * W_ + col;
    float v0 = ip[0];
    float v1 = ip[H_ * W_];
    float v2 = ip[2 * H_ * W_];
    float s  = v0 + v1 + v2;
    float s2 = v0 * v0 + v1 * v1 + v2 * v2;
    block_reduce_2(s, s2);
    float mean = s * (1.0f / PD_);
    float var  = s2 * (1.0f / PD_) - mean * mean;
    float r = rsqrtf(var + EPS_);
    int d = t * 3;
    float* op = out + (size_t)bn * PD_ + d;
    op[0] = (v0 - mean) * r * g[d]     + beta[d];
    op[1] = (v1 - mean) * r * g[d + 1] + beta[d + 1];
    op[2] = (v2 - mean) * r * g[d + 2] + beta[d + 2];
}

// ---------------- row LayerNorm over DIM=1024 (+optional pos_emb) ------------
__global__ void ln_rows(const float* __restrict__ in, float* __restrict__ out,
                        const float* __restrict__ g, const float* __restrict__ beta,
                        const float* __restrict__ pos) {
    int r = blockIdx.x;               // 0..12543
    const float* ip = in + (size_t)r * DIM_;
    float v[4]; float s = 0.f, s2 = 0.f;
    #pragma unroll
    for (int i = 0; i < 4; i++) {
        v[i] = ip[threadIdx.x + 256 * i];
        s += v[i]; s2 += v[i] * v[i];
    }
    block_reduce_2(s, s2);
    float mean = s * (1.0f / DIM_);
    float var  = s2 * (1.0f / DIM_) - mean * mean;
    float rs = rsqrtf(var + EPS_);
    float* op = out + (size_t)r * DIM_;
    int n = r % NP_;
    const float* pp = pos ? (pos + (size_t)n * DIM_) : nullptr;
    #pragma unroll
    for (int i = 0; i < 4; i++) {
        int d = threadIdx.x + 256 * i;
        float o = (v[i] - mean) * rs * g[d] + beta[d];
        if (pp) o += pp[d];
        op[d] = o;
    }
}

// ---------------- general tiled fp32 GEMM ------------------------------------
// C[m,n] = alpha * sum_k A[m,k] * (TRANSB ? B[n,k] : B[k,n])  (+bias[n]) (+resid[m,n])
// batched via blockIdx.z with element strides sa/sb/sc/sr.
template<bool TRANSB>
__global__ void gemm64(const float* __restrict__ A, long sa,
                       const float* __restrict__ Bm, long sb,
                       float* __restrict__ Cm, long sc,
                       const float* __restrict__ bias,
                       const float* __restrict__ resid, long sr,
                       int M, int N, int K, float alpha) {
    __shared__ float As[16][65];
    __shared__ float Bs[16][65];
    int bz = blockIdx.z;
    A  += (size_t)bz * sa;
    Bm += (size_t)bz * sb;
    Cm += (size_t)bz * sc;
    if (resid) resid += (size_t)bz * sr;
    int m0 = blockIdx.y * 64, n0 = blockIdx.x * 64;
    int tid = threadIdx.x;
    int tr = tid >> 4, tc = tid & 15;
    float acc[4][4] = {};
    for (int kk0 = 0; kk0 < K; kk0 += 16) {
        #pragma unroll
        for (int u = 0; u < 4; u++) {
            int e = tid + 256 * u;
            int m = e >> 4, k = e & 15;
            int gm = m0 + m, gk = kk0 + k;
            As[k][m] = (gm < M && gk < K) ? A[(size_t)gm * K + gk] : 0.f;
        }
        if (TRANSB) {
            #pragma unroll
            for (int u = 0; u < 4; u++) {
                int e = tid + 256 * u;
                int n = e >> 4, k = e & 15;
                int gn = n0 + n, gk = kk0 + k;
                Bs[k][n] = (gn < N && gk < K) ? Bm[(size_t)gn * K + gk] : 0.f;
            }
        } else {
            #pragma unroll
            for (int u = 0; u < 4; u++) {
                int e = tid + 256 * u;
                int k = e >> 6, n = e & 63;
                int gk = kk0 + k, gn = n0 + n;
                Bs[k][n] = (gk < K && gn < N) ? Bm[(size_t)gk * N + gn] : 0.f;
            }
        }
        __syncthreads();
        #pragma unroll
        for (int k = 0; k < 16; k++) {
            float a[4], b[4];
            #pragma unroll
            for (int i = 0; i < 4; i++) a[i] = As[k][tr * 4 + i];
            #pragma unroll
            for (int j = 0; j < 4; j++) b[j] = Bs[k][tc * 4 + j];
            #pragma unroll
            for (int i = 0; i < 4; i++)
                #pragma unroll
                for (int j = 0; j < 4; j++)
                    acc[i][j] += a[i] * b[j];
        }
        __syncthreads();
    }
    #pragma unroll
    for (int i = 0; i < 4; i++) {
        int m = m0 + tr * 4 + i;
        if (m >= M) continue;
        #pragma unroll
        for (int j = 0; j < 4; j++) {
            int n = n0 + tc * 4 + j;
            if (n >= N) continue;
            float v = alpha * acc[i][j];
            if (bias)  v += bias[n];
            if (resid) v += resid[(size_t)m * N + n];
            Cm[(size_t)m * N + n] = v;
        }
    }
}

// ---------------- softmax over rows of length 196 ----------------------------
__global__ void softmax196(float* __restrict__ S) {
    __shared__ float red[4];
    int row = blockIdx.x;             // b*196 + n
    float* p = S + (size_t)row * NP_;
    int t = threadIdx.x;
    float v = (t < NP_) ? p[t] : -1e30f;
    float m = v;
    #pragma unroll
    for (int o = 32; o > 0; o >>= 1) m = fmaxf(m, __shfl_down(m, o));
    int lane = t & 63, wid = t >> 6;
    if (lane == 0) red[wid] = m;
    __syncthreads();
    m = fmaxf(fmaxf(red[0], red[1]), fmaxf(red[2], red[3]));
    float e = (t < NP_) ? __expf(v - m) : 0.f;
    float s = e;
    #pragma unroll
    for (int o = 32; o > 0; o >>= 1) s += __shfl_down(s, o);
    __syncthreads();
    if (lane == 0) red[wid] = s;
    __syncthreads();
    s = red[0] + red[1] + red[2] + red[3];
    if (t < NP_) p[t] = e / s;
}

// ---------------- mean-pool over the 196 patches -----------------------------
__global__ void pool_mean(const float* __restrict__ x, float* __restrict__ pooled) {
    int b = blockIdx.x;
    int d = blockIdx.y * 256 + threadIdx.x;   // 0..1023
    const float* p = x + (size_t)b * NP_ * DIM_ + d;
    float s = 0.f;
    for (int n = 0; n < NP_; n++) s += p[(size_t)n * DIM_];
    pooled[(size_t)b * DIM_ + d] = s * (1.0f / NP_);
}

// =============================================================================
extern "C" void kernel_launch(void* const* d_in, const int* in_sizes, int n_in,
                              void* d_out, int out_size, void* d_ws, size_t ws_size,
                              hipStream_t stream) {
    const float* image  = (const float*)d_in[0];
    const float* pos    = (const float*)d_in[1];
    const float* ln_p_g = (const float*)d_in[2];
    const float* ln_p_b = (const float*)d_in[3];
    const float* W_emb  = (const float*)d_in[4];
    const float* b_emb  = (const float*)d_in[5];
    const float* ln_e_g = (const float*)d_in[6];
    const float* ln_e_b = (const float*)d_in[7];
    const float* WV     = (const float*)d_in[8];
    const float* WK     = (const float*)d_in[9];
    const float* WQ     = (const float*)d_in[10];
    const float* ln_g   = (const float*)d_in[11];
    const float* ln_b   = (const float*)d_in[12];
    const float* W_last = (const float*)d_in[13];
    const float* b_last = (const float*)d_in[14];
    float* out = (float*)d_out;

    const size_t SZ = (size_t)ROWS_ * DIM_;      // 12,845,056 floats
    float* x      = (float*)d_ws;                // activations
    float* h      = x + SZ;                      // LN(x)
    float* q      = h + SZ;                      // q; also patchify buf; also fw
    float* k      = q + SZ;                      // k
    float* Abuf   = k + SZ;                      // 64*196*196
    float* pooled = Abuf + (size_t)B_ * NP_ * NP_;

    // 1. patchify + LN_p -> q (as [12544, 768])
    patchify_ln<<<ROWS_, 256, 0, stream>>>(image, ln_p_g, ln_p_b, q);
    // 2. embed GEMM: h = q @ W_emb + b_emb   [12544,1024]
    gemm64<false><<<dim3(16, 196, 1), 256, 0, stream>>>(
        q, 0, W_emb, 0, h, 0, b_emb, nullptr, 0, ROWS_, DIM_, PD_, 1.0f);
    // 3. x = LN_e(h) + pos
    ln_rows<<<ROWS_, 256, 0, stream>>>(h, x, ln_e_g, ln_e_b, pos);

    const long XS = (long)NP_ * DIM_;           // per-batch activation stride
    const long AS = (long)NP_ * NP_;            // per-batch attention stride
    for (int layer = 0; layer < DEPTH_; layer++) {
        // h = LN(x)
        ln_rows<<<ROWS_, 256, 0, stream>>>(x, h, ln_g, ln_b, nullptr);
        // q = h @ WQ ; k = h @ WK
        gemm64<false><<<dim3(16, 196, 1), 256, 0, stream>>>(
            h, 0, WQ, 0, q, 0, nullptr, nullptr, 0, ROWS_, DIM_, DIM_, 1.0f);
        gemm64<false><<<dim3(16, 196, 1), 256, 0, stream>>>(
            h, 0, WK, 0, k, 0, nullptr, nullptr, 0, ROWS_, DIM_, DIM_, 1.0f);
        // S = scale * q @ k^T   (batched over 64)
        gemm64<true><<<dim3(4, 4, B_), 256, 0, stream>>>(
            q, XS, k, XS, Abuf, AS, nullptr, nullptr, 0, NP_, NP_, DIM_, SCALE_);
        // A = softmax(S)
        softmax196<<<ROWS_, 256, 0, stream>>>(Abuf);
        // fw = per-head h @ WV  == [100352,128] @ [128,128] -> reuse q
        gemm64<false><<<dim3(2, 1568, 1), 256, 0, stream>>>(
            h, 0, WV, 0, q, 0, nullptr, nullptr, 0, ROWS_ * HEADS_, VDIM_, VDIM_, 1.0f);
        // x = A @ fw + h   (batched over 64)
        gemm64<false><<<dim3(16, 4, B_), 256, 0, stream>>>(
            Abuf, AS, q, XS, x, XS, nullptr, h, XS, NP_, DIM_, NP_, 1.0f);
    }

    // pooled = mean_n(x)
    pool_mean<<<dim3(B_, 4, 1), 256, 0, stream>>>(x, pooled);
    // out = pooled @ W_last + b_last
    gemm64<false><<<dim3(16, 1, 1), 256, 0, stream>>>(
        pooled, 0, W_last, 0, out, 0, b_last, nullptr, 0, B_, NC_, DIM_, 1.0f);
}

// Round 2
// 2583.554 us; speedup vs baseline: 4.5125x; 4.5125x over previous
//
#include <hip/hip_runtime.h>
#include <stdint.h>

#define B_    64
#define C_    3
#define H_    224
#define W_    224
#define P_    16
#define GH_   14
#define NP_   196
#define PD_   768
#define HEADS_ 8
#define VDIM_ 128
#define DIM_  1024
#define DEPTH_ 6
#define NC_   1000
#define EPS_  1e-5f
#define SCALE_ 0.08838834764831845f   // 128^-0.5
#define ROWS_ (B_*NP_)                 // 12544

typedef __bf16 bf16;
typedef __bf16 bfv8 __attribute__((ext_vector_type(8)));
typedef float  f32x4 __attribute__((ext_vector_type(4)));

#define AS1 __attribute__((address_space(1)))
#define AS3 __attribute__((address_space(3)))

__device__ __forceinline__ void gld_lds16(const bf16* g, bf16* l) {
    __builtin_amdgcn_global_load_lds((const AS1 uint32_t*)g, (AS3 uint32_t*)l, 16, 0, 0);
}

__device__ __forceinline__ f32x4 mfma16(bfv8 a, bfv8 b, f32x4 c) {
    return __builtin_amdgcn_mfma_f32_16x16x32_bf16(a, b, c, 0, 0, 0);
}

// ---------------- block-wide twin reduction ---------------------------------
__device__ inline void block_reduce_2(float& a, float& b) {
    __shared__ float sa[4], sb[4];
    #pragma unroll
    for (int o = 32; o > 0; o >>= 1) {
        a += __shfl_down(a, o);
        b += __shfl_down(b, o);
    }
    int lane = threadIdx.x & 63, wid = threadIdx.x >> 6;
    if (lane == 0) { sa[wid] = a; sb[wid] = b; }
    __syncthreads();
    a = sa[0] + sa[1] + sa[2] + sa[3];
    b = sb[0] + sb[1] + sb[2] + sb[3];
    __syncthreads();
}

// ---------------- patchify + LayerNorm over PD=768 -> bf16 -------------------
__global__ void patchify_ln(const float* __restrict__ img,
                            const float* __restrict__ g,
                            const float* __restrict__ beta,
                            bf16* __restrict__ out) {
    int bn = blockIdx.x;
    int b = bn / NP_, n = bn % NP_;
    int gh = n / GH_, gw = n % GH_;
    int t = threadIdx.x;              // pixel 0..255
    int p1 = t >> 4, p2 = t & 15;
    int row = gh * P_ + p1, col = gw * P_ + p2;
    const float* ip = img + (size_t)b * C_ * H_ * W_ + (size_t)row * W_ + col;
    float v0 = ip[0];
    float v1 = ip[H_ * W_];
    float v2 = ip[2 * H_ * W_];
    float s  = v0 + v1 + v2;
    float s2 = v0 * v0 + v1 * v1 + v2 * v2;
    block_reduce_2(s, s2);
    float mean = s * (1.0f / PD_);
    float var  = s2 * (1.0f / PD_) - mean * mean;
    float r = rsqrtf(var + EPS_);
    int d = t * 3;
    bf16* op = out + (size_t)bn * PD_ + d;
    op[0] = (bf16)((v0 - mean) * r * g[d]     + beta[d]);
    op[1] = (bf16)((v1 - mean) * r * g[d + 1] + beta[d + 1]);
    op[2] = (bf16)((v2 - mean) * r * g[d + 2] + beta[d + 2]);
}

// ---------------- row LayerNorm over DIM=1024 --------------------------------
// writes optional bf16 out and optional fp32 out (+optional pos add)
__global__ void ln_rows(const float* __restrict__ in,
                        bf16* __restrict__ outb, float* __restrict__ outf,
                        const float* __restrict__ g, const float* __restrict__ beta,
                        const float* __restrict__ pos) {
    int r = blockIdx.x;
    const float* ip = in + (size_t)r * DIM_;
    float v[4]; float s = 0.f, s2 = 0.f;
    #pragma unroll
    for (int i = 0; i < 4; i++) {
        v[i] = ip[threadIdx.x + 256 * i];
        s += v[i]; s2 += v[i] * v[i];
    }
    block_reduce_2(s, s2);
    float mean = s * (1.0f / DIM_);
    float var  = s2 * (1.0f / DIM_) - mean * mean;
    float rs = rsqrtf(var + EPS_);
    int n = r % NP_;
    const float* pp = pos ? (pos + (size_t)n * DIM_) : nullptr;
    #pragma unroll
    for (int i = 0; i < 4; i++) {
        int d = threadIdx.x + 256 * i;
        float o = (v[i] - mean) * rs * g[d] + beta[d];
        if (pp) o += pp[d];
        if (outf) outf[(size_t)r * DIM_ + d] = o;
        if (outb) outb[(size_t)r * DIM_ + d] = (bf16)o;
    }
}

// ---------------- big MFMA GEMM: C = A[M,K] @ BT[N,K]^T (+bias) --------------
// requires M%128==0, N%128==0, K%32==0. 256 thr = 4 waves, each 64x64.
template<bool OUT_BF16>
__global__ __launch_bounds__(256)
void gemm_bt_big(const bf16* __restrict__ A, const bf16* __restrict__ BT,
                 void* __restrict__ Cout, const float* __restrict__ bias,
                 int M, int N, int K) {
    __shared__ bf16 Asm[128 * 32];
    __shared__ bf16 Bsm[128 * 32];
    const int tid = threadIdx.x;
    const int wave = tid >> 6, lane = tid & 63;
    const int m0 = blockIdx.y * 128, n0 = blockIdx.x * 128;
    const int r16 = lane >> 2;           // row within 16-row staging group
    const int kc  = (lane & 3) * 8;      // bf16 k-offset (16B chunks)
    const bf16* Ag0 = A  + (size_t)(m0 + wave * 16 + r16) * K + kc;
    const bf16* Ag1 = Ag0 + (size_t)64 * K;
    const bf16* Bg0 = BT + (size_t)(n0 + wave * 16 + r16) * K + kc;
    const bf16* Bg1 = Bg0 + (size_t)64 * K;
    bf16* Al0 = Asm + wave * 512;
    bf16* Al1 = Asm + 2048 + wave * 512;
    bf16* Bl0 = Bsm + wave * 512;
    bf16* Bl1 = Bsm + 2048 + wave * 512;
    const int qd = lane >> 4, l15 = lane & 15;
    const int wm = (wave >> 1) * 64, wn = (wave & 1) * 64;
    f32x4 acc[4][4] = {};
    for (int k0 = 0; k0 < K; k0 += 32) {
        gld_lds16(Ag0 + k0, Al0);
        gld_lds16(Ag1 + k0, Al1);
        gld_lds16(Bg0 + k0, Bl0);
        gld_lds16(Bg1 + k0, Bl1);
        __syncthreads();
        bfv8 af[4], bfr[4];
        #pragma unroll
        for (int i = 0; i < 4; i++)
            af[i] = *(const bfv8*)(Asm + (wm + i * 16 + l15) * 32 + qd * 8);
        #pragma unroll
        for (int j = 0; j < 4; j++)
            bfr[j] = *(const bfv8*)(Bsm + (wn + j * 16 + l15) * 32 + qd * 8);
        #pragma unroll
        for (int i = 0; i < 4; i++)
            #pragma unroll
            for (int j = 0; j < 4; j++)
                acc[i][j] = mfma16(af[i], bfr[j], acc[i][j]);
        __syncthreads();
    }
    float* Cf = (float*)Cout;
    bf16*  Cb = (bf16*)Cout;
    #pragma unroll
    for (int i = 0; i < 4; i++) {
        int rowb = m0 + wm + i * 16 + qd * 4;
        #pragma unroll
        for (int j = 0; j < 4; j++) {
            int col = n0 + wn + j * 16 + l15;
            float bv = bias ? bias[col] : 0.0f;
            #pragma unroll
            for (int r = 0; r < 4; r++) {
                float v = acc[i][j][r] + bv;
                if (OUT_BF16) Cb[(size_t)(rowb + r) * N + col] = (bf16)v;
                else          Cf[(size_t)(rowb + r) * N + col] = v;
            }
        }
    }
}

// ---------------- small MFMA GEMM: 64x64 tile, batched, tail-safe ------------
// C = alpha * A[M,K] @ BT[N,K]^T (+bias) (+resid fp32); VECK => K%32==0 & 16B rows
template<bool VECK, bool OUT_BF16>
__global__ __launch_bounds__(256)
void gemm_bt_small(const bf16* __restrict__ A, long sA, long lda,
                   const bf16* __restrict__ BT, long sB, long ldb,
                   void* __restrict__ Cout, long sC, long ldc,
                   const float* __restrict__ bias,
                   const float* __restrict__ resid, long sR,
                   int M, int N, int K, float alpha) {
    __shared__ bf16 Asm[64 * 32];
    __shared__ bf16 Bsm[64 * 32];
    const int bz = blockIdx.z;
    A  += (size_t)bz * sA;
    BT += (size_t)bz * sB;
    const int tid = threadIdx.x;
    const int wave = tid >> 6, lane = tid & 63;
    const int m0 = blockIdx.y * 64, n0 = blockIdx.x * 64;
    const int srow = tid >> 2;
    const int skc  = (tid & 3) * 8;
    const int qd = lane >> 4, l15 = lane & 15;
    f32x4 acc[4] = {};
    for (int k0 = 0; k0 < K; k0 += 32) {
        {
            bfv8 v = (bfv8)(bf16)0.0f;
            int gm = m0 + srow;
            if (gm < M) {
                if (VECK) {
                    v = *(const bfv8*)(A + (size_t)gm * lda + k0 + skc);
                } else {
                    #pragma unroll
                    for (int e = 0; e < 8; e++) {
                        int k = k0 + skc + e;
                        if (k < K) v[e] = A[(size_t)gm * lda + k];
                    }
                }
            }
            *(bfv8*)(Asm + srow * 32 + skc) = v;
        }
        {
            bfv8 v = (bfv8)(bf16)0.0f;
            int gn = n0 + srow;
            if (gn < N) {
                if (VECK) {
                    v = *(const bfv8*)(BT + (size_t)gn * ldb + k0 + skc);
                } else {
                    #pragma unroll
                    for (int e = 0; e < 8; e++) {
                        int k = k0 + skc + e;
                        if (k < K) v[e] = BT[(size_t)gn * ldb + k];
                    }
                }
            }
            *(bfv8*)(Bsm + srow * 32 + skc) = v;
        }
        __syncthreads();
        bfv8 af = *(const bfv8*)(Asm + (wave * 16 + l15) * 32 + qd * 8);
        #pragma unroll
        for (int j = 0; j < 4; j++) {
            bfv8 bv = *(const bfv8*)(Bsm + (j * 16 + l15) * 32 + qd * 8);
            acc[j] = mfma16(af, bv, acc[j]);
        }
        __syncthreads();
    }
    float* Cf = (float*)Cout + (size_t)bz * sC;
    bf16*  Cb = (bf16*)Cout + (size_t)bz * sC;
    const float* rs = resid ? resid + (size_t)bz * sR : nullptr;
    #pragma unroll
    for (int j = 0; j < 4; j++) {
        int col = n0 + j * 16 + l15;
        if (col >= N) continue;
        float bv = bias ? bias[col] : 0.f;
        #pragma unroll
        for (int r = 0; r < 4; r++) {
            int row = m0 + wave * 16 + qd * 4 + r;
            if (row >= M) continue;
            float v = alpha * acc[j][r] + bv;
            if (rs) v += rs[(size_t)row * ldc + col];
            if (OUT_BF16) Cb[(size_t)row * ldc + col] = (bf16)v;
            else          Cf[(size_t)row * ldc + col] = v;
        }
    }
}

// ---------------- softmax over rows of 196: fp32 in -> bf16 out --------------
__global__ void softmax196(const float* __restrict__ S, bf16* __restrict__ A) {
    __shared__ float red[4];
    int row = blockIdx.x;
    const float* p = S + (size_t)row * NP_;
    int t = threadIdx.x;
    float v = (t < NP_) ? p[t] : -1e30f;
    float m = v;
    #pragma unroll
    for (int o = 32; o > 0; o >>= 1) m = fmaxf(m, __shfl_down(m, o));
    int lane = t & 63, wid = t >> 6;
    if (lane == 0) red[wid] = m;
    __syncthreads();
    m = fmaxf(fmaxf(red[0], red[1]), fmaxf(red[2], red[3]));
    float e = (t < NP_) ? __expf(v - m) : 0.f;
    float s = e;
    #pragma unroll
    for (int o = 32; o > 0; o >>= 1) s += __shfl_down(s, o);
    __syncthreads();
    if (lane == 0) red[wid] = s;
    __syncthreads();
    s = red[0] + red[1] + red[2] + red[3];
    if (t < NP_) A[(size_t)row * NP_ + t] = (bf16)(e / s);
}

// ---------------- transpose+convert fp32 [R,C] -> bf16 [C,R] -----------------
__global__ void transpose_conv(const float* __restrict__ in, bf16* __restrict__ out,
                               int R, int Cc) {
    __shared__ float t[32][33];
    int c0 = blockIdx.x * 32, r0 = blockIdx.y * 32;
    int tx = threadIdx.x & 31, ty = threadIdx.x >> 5;   // 32 x 8
    #pragma unroll
    for (int i = 0; i < 4; i++) {
        int r = r0 + ty + i * 8;
        if (r < R && c0 + tx < Cc) t[ty + i * 8][tx] = in[(size_t)r * Cc + c0 + tx];
    }
    __syncthreads();
    #pragma unroll
    for (int i = 0; i < 4; i++) {
        int c = c0 + ty + i * 8, r = r0 + tx;
        if (c < Cc && r < R) out[(size_t)c * R + r] = (bf16)t[tx][ty + i * 8];
    }
}

// ---------------- per-batch transpose: fw[b][196][1024] -> fwT[b][1024][196] -
__global__ void transpose_fw(const bf16* __restrict__ fw, bf16* __restrict__ fwT) {
    __shared__ bf16 t[32][33];
    int b = blockIdx.z;
    int d0 = blockIdx.x * 32, n0 = blockIdx.y * 32;
    int tx = threadIdx.x & 31, ty = threadIdx.x >> 5;
    #pragma unroll
    for (int i = 0; i < 4; i++) {
        int n = n0 + ty + i * 8;
        if (n < NP_) t[ty + i * 8][tx] = fw[((size_t)b * NP_ + n) * DIM_ + d0 + tx];
    }
    __syncthreads();
    #pragma unroll
    for (int i = 0; i < 4; i++) {
        int d = d0 + ty + i * 8, n = n0 + tx;
        if (n < NP_) fwT[(size_t)b * DIM_ * NP_ + (size_t)d * NP_ + n] = t[tx][ty + i * 8];
    }
}

// ---------------- mean-pool over 196 patches: fp32 in -> bf16 out ------------
__global__ void pool_mean(const float* __restrict__ x, bf16* __restrict__ pooled) {
    int b = blockIdx.x;
    int d = blockIdx.y * 256 + threadIdx.x;
    const float* p = x + (size_t)b * NP_ * DIM_ + d;
    float s = 0.f;
    for (int n = 0; n < NP_; n++) s += p[(size_t)n * DIM_];
    pooled[(size_t)b * DIM_ + d] = (bf16)(s * (1.0f / NP_));
}

// =============================================================================
extern "C" void kernel_launch(void* const* d_in, const int* in_sizes, int n_in,
                              void* d_out, int out_size, void* d_ws, size_t ws_size,
                              hipStream_t stream) {
    const float* image  = (const float*)d_in[0];
    const float* pos    = (const float*)d_in[1];
    const float* ln_p_g = (const float*)d_in[2];
    const float* ln_p_b = (const float*)d_in[3];
    const float* W_emb  = (const float*)d_in[4];
    const float* b_emb  = (const float*)d_in[5];
    const float* ln_e_g = (const float*)d_in[6];
    const float* ln_e_b = (const float*)d_in[7];
    const float* WV     = (const float*)d_in[8];
    const float* WK     = (const float*)d_in[9];
    const float* WQ     = (const float*)d_in[10];
    const float* ln_g   = (const float*)d_in[11];
    const float* ln_b   = (const float*)d_in[12];
    const float* W_last = (const float*)d_in[13];
    const float* b_last = (const float*)d_in[14];
    float* out = (float*)d_out;

    char* p = (char*)d_ws;
    auto alloc = [&](size_t bytes) { char* r = p; p += (bytes + 255) & ~(size_t)255; return r; };
    float* x      = (float*)alloc((size_t)ROWS_ * DIM_ * 4);
    float* hf     = (float*)alloc((size_t)ROWS_ * DIM_ * 4);
    bf16*  h_bf   = (bf16*) alloc((size_t)ROWS_ * DIM_ * 2);
    bf16*  q_bf   = (bf16*) alloc((size_t)ROWS_ * DIM_ * 2);   // also patch_bf, fw
    bf16*  k_bf   = (bf16*) alloc((size_t)ROWS_ * DIM_ * 2);   // also fwT
    float* S      = (float*)alloc((size_t)B_ * NP_ * NP_ * 4);
    bf16*  A_bf   = (bf16*) alloc((size_t)B_ * NP_ * NP_ * 2);
    bf16*  WembT  = (bf16*) alloc((size_t)DIM_ * PD_ * 2);
    bf16*  WQT    = (bf16*) alloc((size_t)DIM_ * DIM_ * 2);
    bf16*  WKT    = (bf16*) alloc((size_t)DIM_ * DIM_ * 2);
    bf16*  WVT    = (bf16*) alloc((size_t)VDIM_ * VDIM_ * 2);
    bf16*  WlastT = (bf16*) alloc((size_t)NC_ * DIM_ * 2);
    bf16*  pooled = (bf16*) alloc((size_t)B_ * DIM_ * 2);

    // --- weight prep (transpose + fp32->bf16), once per call -----------------
    transpose_conv<<<dim3(32, 24), 256, 0, stream>>>(W_emb,  WembT,  PD_,  DIM_);
    transpose_conv<<<dim3(32, 32), 256, 0, stream>>>(WQ,     WQT,    DIM_, DIM_);
    transpose_conv<<<dim3(32, 32), 256, 0, stream>>>(WK,     WKT,    DIM_, DIM_);
    transpose_conv<<<dim3(4, 4),   256, 0, stream>>>(WV,     WVT,    VDIM_, VDIM_);
    transpose_conv<<<dim3(32, 32), 256, 0, stream>>>(W_last, WlastT, DIM_, NC_);

    // --- stem ----------------------------------------------------------------
    patchify_ln<<<ROWS_, 256, 0, stream>>>(image, ln_p_g, ln_p_b, q_bf);
    gemm_bt_big<false><<<dim3(DIM_ / 128, ROWS_ / 128), 256, 0, stream>>>(
        q_bf, WembT, hf, b_emb, ROWS_, DIM_, PD_);
    ln_rows<<<ROWS_, 256, 0, stream>>>(hf, nullptr, x, ln_e_g, ln_e_b, pos);

    const long XS = (long)NP_ * DIM_;
    const long AS = (long)NP_ * NP_;
    for (int layer = 0; layer < DEPTH_; layer++) {
        ln_rows<<<ROWS_, 256, 0, stream>>>(x, h_bf, hf, ln_g, ln_b, nullptr);
        gemm_bt_big<true><<<dim3(DIM_ / 128, ROWS_ / 128), 256, 0, stream>>>(
            h_bf, WQT, q_bf, nullptr, ROWS_, DIM_, DIM_);
        gemm_bt_big<true><<<dim3(DIM_ / 128, ROWS_ / 128), 256, 0, stream>>>(
            h_bf, WKT, k_bf, nullptr, ROWS_, DIM_, DIM_);
        // S = scale * q @ k^T  (batched)
        gemm_bt_small<true, false><<<dim3(4, 4, B_), 256, 0, stream>>>(
            q_bf, XS, DIM_, k_bf, XS, DIM_, S, AS, NP_,
            nullptr, nullptr, 0, NP_, NP_, DIM_, SCALE_);
        softmax196<<<ROWS_, 256, 0, stream>>>(S, A_bf);
        // fw = per-head h @ WV  (h viewed [ROWS*8,128]) -> q_bf (bf16)
        gemm_bt_small<true, true><<<dim3(2, 1568, 1), 256, 0, stream>>>(
            h_bf, 0, VDIM_, WVT, 0, VDIM_, q_bf, 0, VDIM_,
            nullptr, nullptr, 0, ROWS_ * HEADS_, VDIM_, VDIM_, 1.0f);
        // fwT[b] = fw[b]^T  -> k_bf
        transpose_fw<<<dim3(32, 7, B_), 256, 0, stream>>>(q_bf, k_bf);
        // x = A @ fw + hf  (batched, K=196 tail-safe)
        gemm_bt_small<false, false><<<dim3(16, 4, B_), 256, 0, stream>>>(
            A_bf, AS, NP_, k_bf, XS, NP_, x, XS, DIM_,
            nullptr, hf, XS, NP_, DIM_, NP_, 1.0f);
    }

    pool_mean<<<dim3(B_, 4), 256, 0, stream>>>(x, pooled);
    gemm_bt_small<true, false><<<dim3(16, 1, 1), 256, 0, stream>>>(
        pooled, 0, DIM_, WlastT, 0, DIM_, out, 0, NC_,
        b_last, nullptr, 0, B_, NC_, DIM_, 1.0f);
}

// Round 4
// 1711.620 us; speedup vs baseline: 6.8113x; 1.5094x over previous
//
#include <hip/hip_runtime.h>
#include <stdint.h>

#define B_    64
#define C_    3
#define H_    224
#define W_    224
#define P_    16
#define GH_   14
#define NP_   196
#define NPP_  224          // NP padded to multiple of 32
#define PD_   768
#define HEADS_ 8
#define VDIM_ 128
#define DIM_  1024
#define DEPTH_ 6
#define NC_   1000
#define EPS_  1e-5f
#define SCALE_ 0.08838834764831845f   // 128^-0.5
#define ROWS_ (B_*NP_)                 // 12544

typedef __bf16 bf16;
typedef __bf16 bfv8 __attribute__((ext_vector_type(8)));
typedef float  f32x4 __attribute__((ext_vector_type(4)));

#define AS1 __attribute__((address_space(1)))
#define AS3 __attribute__((address_space(3)))

__device__ __forceinline__ void gld_lds16(const bf16* g, bf16* l) {
    __builtin_amdgcn_global_load_lds((const AS1 uint32_t*)g, (AS3 uint32_t*)l, 16, 0, 0);
}

__device__ __forceinline__ f32x4 mfma16(bfv8 a, bfv8 b, f32x4 c) {
    return __builtin_amdgcn_mfma_f32_16x16x32_bf16(a, b, c, 0, 0, 0);
}

// ---------------- zero-fill (float4 grid-stride) -----------------------------
__global__ void zero_f4(float4* __restrict__ p, size_t n4) {
    size_t i = (size_t)blockIdx.x * blockDim.x + threadIdx.x;
    size_t stride = (size_t)gridDim.x * blockDim.x;
    float4 z = {0.f, 0.f, 0.f, 0.f};
    for (; i < n4; i += stride) p[i] = z;
}

// ---------------- block-wide twin reduction ---------------------------------
__device__ inline void block_reduce_2(float& a, float& b) {
    __shared__ float sa[4], sb[4];
    #pragma unroll
    for (int o = 32; o > 0; o >>= 1) {
        a += __shfl_down(a, o);
        b += __shfl_down(b, o);
    }
    int lane = threadIdx.x & 63, wid = threadIdx.x >> 6;
    if (lane == 0) { sa[wid] = a; sb[wid] = b; }
    __syncthreads();
    a = sa[0] + sa[1] + sa[2] + sa[3];
    b = sb[0] + sb[1] + sb[2] + sb[3];
    __syncthreads();
}

// ---------------- patchify + LayerNorm over PD=768 -> bf16 -------------------
__global__ void patchify_ln(const float* __restrict__ img,
                            const float* __restrict__ g,
                            const float* __restrict__ beta,
                            bf16* __restrict__ out) {
    int bn = blockIdx.x;
    int b = bn / NP_, n = bn % NP_;
    int gh = n / GH_, gw = n % GH_;
    int t = threadIdx.x;              // pixel 0..255
    int p1 = t >> 4, p2 = t & 15;
    int row = gh * P_ + p1, col = gw * P_ + p2;
    const float* ip = img + (size_t)b * C_ * H_ * W_ + (size_t)row * W_ + col;
    float v0 = ip[0];
    float v1 = ip[H_ * W_];
    float v2 = ip[2 * H_ * W_];
    float s  = v0 + v1 + v2;
    float s2 = v0 * v0 + v1 * v1 + v2 * v2;
    block_reduce_2(s, s2);
    float mean = s * (1.0f / PD_);
    float var  = s2 * (1.0f / PD_) - mean * mean;
    float r = rsqrtf(var + EPS_);
    int d = t * 3;
    bf16* op = out + (size_t)bn * PD_ + d;
    op[0] = (bf16)((v0 - mean) * r * g[d]     + beta[d]);
    op[1] = (bf16)((v1 - mean) * r * g[d + 1] + beta[d + 1]);
    op[2] = (bf16)((v2 - mean) * r * g[d + 2] + beta[d + 2]);
}

// ---------------- row LayerNorm over DIM=1024 --------------------------------
__global__ void ln_rows(const float* __restrict__ in,
                        bf16* __restrict__ outb, float* __restrict__ outf,
                        const float* __restrict__ g, const float* __restrict__ beta,
                        const float* __restrict__ pos) {
    int r = blockIdx.x;
    const float* ip = in + (size_t)r * DIM_;
    float v[4]; float s = 0.f, s2 = 0.f;
    #pragma unroll
    for (int i = 0; i < 4; i++) {
        v[i] = ip[threadIdx.x + 256 * i];
        s += v[i]; s2 += v[i] * v[i];
    }
    block_reduce_2(s, s2);
    float mean = s * (1.0f / DIM_);
    float var  = s2 * (1.0f / DIM_) - mean * mean;
    float rs = rsqrtf(var + EPS_);
    int n = r % NP_;
    const float* pp = pos ? (pos + (size_t)n * DIM_) : nullptr;
    #pragma unroll
    for (int i = 0; i < 4; i++) {
        int d = threadIdx.x + 256 * i;
        float o = (v[i] - mean) * rs * g[d] + beta[d];
        if (pp) o += pp[d];
        if (outf) outf[(size_t)r * DIM_ + d] = o;
        if (outb) outb[(size_t)r * DIM_ + d] = (bf16)o;
    }
}

// ---------------- big MFMA GEMM: C = A[M,K] @ BT[N,K]^T (+bias) --------------
// requires M%128==0, N%128==0, K%32==0. 256 thr = 4 waves, each 64x64.
template<bool OUT_BF16>
__global__ __launch_bounds__(256)
void gemm_bt_big(const bf16* __restrict__ A, const bf16* __restrict__ BT,
                 void* __restrict__ Cout, const float* __restrict__ bias,
                 int M, int N, int K) {
    __shared__ bf16 Asm[128 * 32];
    __shared__ bf16 Bsm[128 * 32];
    const int tid = threadIdx.x;
    const int wave = tid >> 6, lane = tid & 63;
    const int m0 = blockIdx.y * 128, n0 = blockIdx.x * 128;
    const int r16 = lane >> 2;
    const int kc  = (lane & 3) * 8;
    const bf16* Ag0 = A  + (size_t)(m0 + wave * 16 + r16) * K + kc;
    const bf16* Ag1 = Ag0 + (size_t)64 * K;
    const bf16* Bg0 = BT + (size_t)(n0 + wave * 16 + r16) * K + kc;
    const bf16* Bg1 = Bg0 + (size_t)64 * K;
    bf16* Al0 = Asm + wave * 512;
    bf16* Al1 = Asm + 2048 + wave * 512;
    bf16* Bl0 = Bsm + wave * 512;
    bf16* Bl1 = Bsm + 2048 + wave * 512;
    const int qd = lane >> 4, l15 = lane & 15;
    const int wm = (wave >> 1) * 64, wn = (wave & 1) * 64;
    f32x4 acc[4][4] = {};
    for (int k0 = 0; k0 < K; k0 += 32) {
        gld_lds16(Ag0 + k0, Al0);
        gld_lds16(Ag1 + k0, Al1);
        gld_lds16(Bg0 + k0, Bl0);
        gld_lds16(Bg1 + k0, Bl1);
        __syncthreads();
        bfv8 af[4], bfr[4];
        #pragma unroll
        for (int i = 0; i < 4; i++)
            af[i] = *(const bfv8*)(Asm + (wm + i * 16 + l15) * 32 + qd * 8);
        #pragma unroll
        for (int j = 0; j < 4; j++)
            bfr[j] = *(const bfv8*)(Bsm + (wn + j * 16 + l15) * 32 + qd * 8);
        #pragma unroll
        for (int i = 0; i < 4; i++)
            #pragma unroll
            for (int j = 0; j < 4; j++)
                acc[i][j] = mfma16(af[i], bfr[j], acc[i][j]);
        __syncthreads();
    }
    float* Cf = (float*)Cout;
    bf16*  Cb = (bf16*)Cout;
    #pragma unroll
    for (int i = 0; i < 4; i++) {
        int rowb = m0 + wm + i * 16 + qd * 4;
        #pragma unroll
        for (int j = 0; j < 4; j++) {
            int col = n0 + wn + j * 16 + l15;
            float bv = bias ? bias[col] : 0.0f;
            #pragma unroll
            for (int r = 0; r < 4; r++) {
                float v = acc[i][j][r] + bv;
                if (OUT_BF16) Cb[(size_t)(rowb + r) * N + col] = (bf16)v;
                else          Cf[(size_t)(rowb + r) * N + col] = v;
            }
        }
    }
}

// ---------------- small MFMA GEMM: 64x64 tile, 2-level batch, tail-safe ------
// z = blockIdx.z; z1 = z/zdiv, z2 = z%zdiv; ptr += z1*s?1 + z2*s?2
// C = alpha * A[M,K] @ BT[N,K]^T (+bias[col]) (+resid bf16, pitch ldc)
// LDS pitch 32 (64B rows) — identical layout to the round-2 passing kernel.
template<bool VECK, bool OUT_BF16>
__global__ __launch_bounds__(256)
void gemm_bt_small(const bf16* __restrict__ A, long sA1, long sA2, long lda,
                   const bf16* __restrict__ BT, long sB1, long sB2, long ldb,
                   void* __restrict__ Cout, long sC1, long sC2, long ldc,
                   const float* __restrict__ bias,
                   const bf16* __restrict__ resid, long sR1,
                   int M, int N, int K, float alpha, int zdiv) {
    __shared__ bf16 Asm[64 * 32];
    __shared__ bf16 Bsm[64 * 32];
    const int bz = blockIdx.z;
    const int z1 = bz / zdiv, z2 = bz % zdiv;
    A  += (size_t)z1 * sA1 + (size_t)z2 * sA2;
    BT += (size_t)z1 * sB1 + (size_t)z2 * sB2;
    const int tid = threadIdx.x;
    const int wave = tid >> 6, lane = tid & 63;
    const int m0 = blockIdx.y * 64, n0 = blockIdx.x * 64;
    const int srow = tid >> 2;
    const int skc  = (tid & 3) * 8;
    const int qd = lane >> 4, l15 = lane & 15;
    f32x4 acc[4] = {};
    for (int k0 = 0; k0 < K; k0 += 32) {
        {
            bfv8 v = (bfv8)(bf16)0.0f;
            int gm = m0 + srow;
            if (gm < M) {
                if (VECK) {
                    v = *(const bfv8*)(A + (size_t)gm * lda + k0 + skc);
                } else {
                    #pragma unroll
                    for (int e = 0; e < 8; e++) {
                        int k = k0 + skc + e;
                        if (k < K) v[e] = A[(size_t)gm * lda + k];
                    }
                }
            }
            *(bfv8*)(Asm + srow * 32 + skc) = v;
        }
        {
            bfv8 v = (bfv8)(bf16)0.0f;
            int gn = n0 + srow;
            if (gn < N) {
                if (VECK) {
                    v = *(const bfv8*)(BT + (size_t)gn * ldb + k0 + skc);
                } else {
                    #pragma unroll
                    for (int e = 0; e < 8; e++) {
                        int k = k0 + skc + e;
                        if (k < K) v[e] = BT[(size_t)gn * ldb + k];
                    }
                }
            }
            *(bfv8*)(Bsm + srow * 32 + skc) = v;
        }
        __syncthreads();
        bfv8 af = *(const bfv8*)(Asm + (wave * 16 + l15) * 32 + qd * 8);
        #pragma unroll
        for (int j = 0; j < 4; j++) {
            bfv8 bv = *(const bfv8*)(Bsm + (j * 16 + l15) * 32 + qd * 8);
            acc[j] = mfma16(af, bv, acc[j]);
        }
        __syncthreads();
    }
    float* Cf = (float*)Cout + (size_t)z1 * sC1 + (size_t)z2 * sC2;
    bf16*  Cb = (bf16*)Cout + (size_t)z1 * sC1 + (size_t)z2 * sC2;
    const bf16* rs = resid ? resid + (size_t)z1 * sR1 : nullptr;
    #pragma unroll
    for (int j = 0; j < 4; j++) {
        int col = n0 + j * 16 + l15;
        if (col >= N) continue;
        float bv = bias ? bias[col] : 0.f;
        #pragma unroll
        for (int r = 0; r < 4; r++) {
            int row = m0 + wave * 16 + qd * 4 + r;
            if (row >= M) continue;
            float v = alpha * acc[j][r] + bv;
            if (rs) v += (float)rs[(size_t)row * ldc + col];
            if (OUT_BF16) Cb[(size_t)row * ldc + col] = (bf16)v;
            else          Cf[(size_t)row * ldc + col] = v;
        }
    }
}

// ------- softmax over rows of 196: fp32 in -> bf16 PADDED out [b][224][224] --
__global__ void softmax196(const float* __restrict__ S, bf16* __restrict__ Apad) {
    __shared__ float red[4];
    int row = blockIdx.x;             // b*196 + n
    int b = row / NP_, n = row % NP_;
    const float* p = S + (size_t)row * NP_;
    int t = threadIdx.x;
    float v = (t < NP_) ? p[t] : -1e30f;
    float m = v;
    #pragma unroll
    for (int o = 32; o > 0; o >>= 1) m = fmaxf(m, __shfl_down(m, o));
    int lane = t & 63, wid = t >> 6;
    if (lane == 0) red[wid] = m;
    __syncthreads();
    m = fmaxf(fmaxf(red[0], red[1]), fmaxf(red[2], red[3]));
    float e = (t < NP_) ? __expf(v - m) : 0.f;
    float s = e;
    #pragma unroll
    for (int o = 32; o > 0; o >>= 1) s += __shfl_down(s, o);
    __syncthreads();
    if (lane == 0) red[wid] = s;
    __syncthreads();
    s = red[0] + red[1] + red[2] + red[3];
    if (t < NPP_) {
        bf16* op = Apad + ((size_t)b * NPP_ + n) * NPP_;
        op[t] = (bf16)((t < NP_) ? (e / s) : 0.f);
    }
}

// ---------------- transpose+convert fp32 [R,C] -> bf16 [C,R] -----------------
__global__ void transpose_conv(const float* __restrict__ in, bf16* __restrict__ out,
                               int R, int Cc) {
    __shared__ float t[32][33];
    int c0 = blockIdx.x * 32, r0 = blockIdx.y * 32;
    int tx = threadIdx.x & 31, ty = threadIdx.x >> 5;   // 32 x 8
    #pragma unroll
    for (int i = 0; i < 4; i++) {
        int r = r0 + ty + i * 8;
        if (r < R && c0 + tx < Cc) t[ty + i * 8][tx] = in[(size_t)r * Cc + c0 + tx];
    }
    __syncthreads();
    #pragma unroll
    for (int i = 0; i < 4; i++) {
        int c = c0 + ty + i * 8, r = r0 + tx;
        if (c < Cc && r < R) out[(size_t)c * R + r] = (bf16)t[tx][ty + i * 8];
    }
}

// ---------------- mean-pool over 196 patches: fp32 in -> bf16 out ------------
__global__ void pool_mean(const float* __restrict__ x, bf16* __restrict__ pooled) {
    int b = blockIdx.x;
    int d = blockIdx.y * 256 + threadIdx.x;
    const float* p = x + (size_t)b * NP_ * DIM_ + d;
    float s = 0.f;
    for (int n = 0; n < NP_; n++) s += p[(size_t)n * DIM_];
    pooled[(size_t)b * DIM_ + d] = (bf16)(s * (1.0f / NP_));
}

// =============================================================================
extern "C" void kernel_launch(void* const* d_in, const int* in_sizes, int n_in,
                              void* d_out, int out_size, void* d_ws, size_t ws_size,
                              hipStream_t stream) {
    const float* image  = (const float*)d_in[0];
    const float* pos    = (const float*)d_in[1];
    const float* ln_p_g = (const float*)d_in[2];
    const float* ln_p_b = (const float*)d_in[3];
    const float* W_emb  = (const float*)d_in[4];
    const float* b_emb  = (const float*)d_in[5];
    const float* ln_e_g = (const float*)d_in[6];
    const float* ln_e_b = (const float*)d_in[7];
    const float* WV     = (const float*)d_in[8];
    const float* WK     = (const float*)d_in[9];
    const float* WQ     = (const float*)d_in[10];
    const float* ln_g   = (const float*)d_in[11];
    const float* ln_b   = (const float*)d_in[12];
    const float* W_last = (const float*)d_in[13];
    const float* b_last = (const float*)d_in[14];
    float* out = (float*)d_out;

    char* p = (char*)d_ws;
    auto alloc = [&](size_t bytes) { char* r = p; p += (bytes + 255) & ~(size_t)255; return r; };
    float* x   = (float*)alloc((size_t)ROWS_ * DIM_ * 4);   // 51.38 MB fp32 stream
    // region (51.38 MB): stem hf (fp32, consumed before layers) overlays
    // {S | A_pad | fwT} which are live only inside the layer loop.
    char*  region = alloc((size_t)ROWS_ * DIM_ * 4);
    float* hf    = (float*)region;
    float* S     = (float*)region;                              // 9,834,496 B
    bf16*  A_pad = (bf16*)(region + 9834496);                   // 6,422,528 B
    bf16*  fwT   = (bf16*)(region + 9834496 + 6422528);         // 29,360,128 B
    bf16*  h_bf  = (bf16*)alloc((size_t)ROWS_ * DIM_ * 2);
    bf16*  q_bf  = (bf16*)alloc((size_t)ROWS_ * DIM_ * 2);
    bf16*  k_bf  = (bf16*)alloc((size_t)ROWS_ * DIM_ * 2);
    bf16*  WembT  = (bf16*)alloc((size_t)DIM_ * PD_ * 2);
    bf16*  WQT    = (bf16*)alloc((size_t)DIM_ * DIM_ * 2);
    bf16*  WKT    = (bf16*)alloc((size_t)DIM_ * DIM_ * 2);
    bf16*  WVT    = (bf16*)alloc((size_t)VDIM_ * VDIM_ * 2);
    bf16*  WlastT = (bf16*)alloc((size_t)NC_ * DIM_ * 2);
    bf16*  pooled = (bf16*)alloc((size_t)B_ * DIM_ * 2);

    // --- weight prep (transpose + fp32->bf16), once per call -----------------
    transpose_conv<<<dim3(32, 24), 256, 0, stream>>>(W_emb,  WembT,  PD_,  DIM_);
    transpose_conv<<<dim3(32, 32), 256, 0, stream>>>(WQ,     WQT,    DIM_, DIM_);
    transpose_conv<<<dim3(32, 32), 256, 0, stream>>>(WK,     WKT,    DIM_, DIM_);
    transpose_conv<<<dim3(4, 4),   256, 0, stream>>>(WV,     WVT,    VDIM_, VDIM_);
    transpose_conv<<<dim3(32, 32), 256, 0, stream>>>(W_last, WlastT, DIM_, NC_);

    // --- stem ----------------------------------------------------------------
    patchify_ln<<<ROWS_, 256, 0, stream>>>(image, ln_p_g, ln_p_b, q_bf);
    gemm_bt_big<false><<<dim3(DIM_ / 128, ROWS_ / 128), 256, 0, stream>>>(
        q_bf, WembT, hf, b_emb, ROWS_, DIM_, PD_);
    ln_rows<<<ROWS_, 256, 0, stream>>>(hf, nullptr, x, ln_e_g, ln_e_b, pos);

    // --- zero A_pad + fwT (adjacent, 35,782,656 B = 2,236,416 float4) --------
    // after stem hf is consumed; pads stay zero through all layers.
    zero_f4<<<2048, 256, 0, stream>>>((float4*)A_pad, (size_t)35782656 / 16);

    const long XS  = (long)NP_ * DIM_;      // activation per-batch stride
    const long AS  = (long)NP_ * NP_;       // S per-batch stride
    const long APS = (long)NPP_ * NPP_;     // padded A per-batch stride
    const long FTS = (long)DIM_ * NPP_;     // fwT per-batch stride
    for (int layer = 0; layer < DEPTH_; layer++) {
        // h = LN(x)  (bf16)
        ln_rows<<<ROWS_, 256, 0, stream>>>(x, h_bf, nullptr, ln_g, ln_b, nullptr);
        // q = h @ WQ ; k = h @ WK
        gemm_bt_big<true><<<dim3(DIM_ / 128, ROWS_ / 128), 256, 0, stream>>>(
            h_bf, WQT, q_bf, nullptr, ROWS_, DIM_, DIM_);
        gemm_bt_big<true><<<dim3(DIM_ / 128, ROWS_ / 128), 256, 0, stream>>>(
            h_bf, WKT, k_bf, nullptr, ROWS_, DIM_, DIM_);
        // S = scale * q @ k^T   (batched over b)
        gemm_bt_small<true, false><<<dim3(4, 4, B_), 256, 0, stream>>>(
            q_bf, XS, 0, DIM_, k_bf, XS, 0, DIM_, S, AS, 0, NP_,
            nullptr, nullptr, 0, NP_, NP_, DIM_, SCALE_, 1);
        // A_pad = softmax(S), cols zero-padded to 224
        softmax196<<<ROWS_, 256, 0, stream>>>(S, A_pad);
        // fwT[b][hd*128+dv][n] = sum_k WVT[dv][k] * h[b][n][hd*128+k]
        //   z = b*8 + hd
        gemm_bt_small<true, true><<<dim3(4, 2, B_ * HEADS_), 256, 0, stream>>>(
            WVT, 0, 0, VDIM_,
            h_bf, XS, VDIM_, DIM_,
            fwT, FTS, (long)VDIM_ * NPP_, NPP_,
            nullptr, nullptr, 0, VDIM_, NP_, VDIM_, 1.0f, HEADS_);
        // x = A_pad @ fwT^T + h   (batched over b; K=224 vectorized)
        gemm_bt_small<true, false><<<dim3(16, 4, B_), 256, 0, stream>>>(
            A_pad, APS, 0, NPP_, fwT, FTS, 0, NPP_, x, XS, 0, DIM_,
            nullptr, h_bf, XS, NP_, DIM_, NPP_, 1.0f, 1);
    }

    pool_mean<<<dim3(B_, 4), 256, 0, stream>>>(x, pooled);
    gemm_bt_small<true, false><<<dim3(16, 1, 1), 256, 0, stream>>>(
        pooled, 0, 0, DIM_, WlastT, 0, 0, DIM_, out, 0, 0, NC_,
        b_last, nullptr, 0, B_, NC_, DIM_, 1.0f, 1);
}

// Round 5
// 1532.789 us; speedup vs baseline: 7.6059x; 1.1167x over previous
//
#include <hip/hip_runtime.h>
#include <stdint.h>

#define B_    64
#define C_    3
#define H_    224
#define W_    224
#define P_    16
#define GH_   14
#define NP_   196
#define NPP_  224          // NP padded to multiple of 32
#define PD_   768
#define HEADS_ 8
#define VDIM_ 128
#define DIM_  1024
#define QKD_  2048         // fused Q|K output width
#define DEPTH_ 6
#define NC_   1000
#define EPS_  1e-5f
#define SCALE_ 0.08838834764831845f   // 128^-0.5
#define ROWS_ (B_*NP_)                 // 12544

typedef __bf16 bf16;
typedef __bf16 bfv8 __attribute__((ext_vector_type(8)));
typedef float  f32x4 __attribute__((ext_vector_type(4)));

#define AS1 __attribute__((address_space(1)))
#define AS3 __attribute__((address_space(3)))

__device__ __forceinline__ void gld_lds16(const bf16* g, bf16* l) {
    __builtin_amdgcn_global_load_lds((const AS1 uint32_t*)g, (AS3 uint32_t*)l, 16, 0, 0);
}

__device__ __forceinline__ f32x4 mfma16(bfv8 a, bfv8 b, f32x4 c) {
    return __builtin_amdgcn_mfma_f32_16x16x32_bf16(a, b, c, 0, 0, 0);
}

// ---------------- zero-fill (float4 grid-stride) -----------------------------
__global__ void zero_f4(float4* __restrict__ p, size_t n4) {
    size_t i = (size_t)blockIdx.x * blockDim.x + threadIdx.x;
    size_t stride = (size_t)gridDim.x * blockDim.x;
    float4 z = {0.f, 0.f, 0.f, 0.f};
    for (; i < n4; i += stride) p[i] = z;
}

// ---------------- block-wide twin reduction ---------------------------------
__device__ inline void block_reduce_2(float& a, float& b) {
    __shared__ float sa[4], sb[4];
    #pragma unroll
    for (int o = 32; o > 0; o >>= 1) {
        a += __shfl_down(a, o);
        b += __shfl_down(b, o);
    }
    int lane = threadIdx.x & 63, wid = threadIdx.x >> 6;
    if (lane == 0) { sa[wid] = a; sb[wid] = b; }
    __syncthreads();
    a = sa[0] + sa[1] + sa[2] + sa[3];
    b = sb[0] + sb[1] + sb[2] + sb[3];
    __syncthreads();
}

// ---------------- patchify + LayerNorm over PD=768 -> bf16 -------------------
__global__ void patchify_ln(const float* __restrict__ img,
                            const float* __restrict__ g,
                            const float* __restrict__ beta,
                            bf16* __restrict__ out) {
    int bn = blockIdx.x;
    int b = bn / NP_, n = bn % NP_;
    int gh = n / GH_, gw = n % GH_;
    int t = threadIdx.x;              // pixel 0..255
    int p1 = t >> 4, p2 = t & 15;
    int row = gh * P_ + p1, col = gw * P_ + p2;
    const float* ip = img + (size_t)b * C_ * H_ * W_ + (size_t)row * W_ + col;
    float v0 = ip[0];
    float v1 = ip[H_ * W_];
    float v2 = ip[2 * H_ * W_];
    float s  = v0 + v1 + v2;
    float s2 = v0 * v0 + v1 * v1 + v2 * v2;
    block_reduce_2(s, s2);
    float mean = s * (1.0f / PD_);
    float var  = s2 * (1.0f / PD_) - mean * mean;
    float r = rsqrtf(var + EPS_);
    int d = t * 3;
    bf16* op = out + (size_t)bn * PD_ + d;
    op[0] = (bf16)((v0 - mean) * r * g[d]     + beta[d]);
    op[1] = (bf16)((v1 - mean) * r * g[d + 1] + beta[d + 1]);
    op[2] = (bf16)((v2 - mean) * r * g[d + 2] + beta[d + 2]);
}

// ---------------- row LayerNorm over DIM=1024 --------------------------------
__global__ void ln_rows(const float* __restrict__ in,
                        bf16* __restrict__ outb, float* __restrict__ outf,
                        const float* __restrict__ g, const float* __restrict__ beta,
                        const float* __restrict__ pos) {
    int r = blockIdx.x;
    const float* ip = in + (size_t)r * DIM_;
    float v[4]; float s = 0.f, s2 = 0.f;
    #pragma unroll
    for (int i = 0; i < 4; i++) {
        v[i] = ip[threadIdx.x + 256 * i];
        s += v[i]; s2 += v[i] * v[i];
    }
    block_reduce_2(s, s2);
    float mean = s * (1.0f / DIM_);
    float var  = s2 * (1.0f / DIM_) - mean * mean;
    float rs = rsqrtf(var + EPS_);
    int n = r % NP_;
    const float* pp = pos ? (pos + (size_t)n * DIM_) : nullptr;
    #pragma unroll
    for (int i = 0; i < 4; i++) {
        int d = threadIdx.x + 256 * i;
        float o = (v[i] - mean) * rs * g[d] + beta[d];
        if (pp) o += pp[d];
        if (outf) outf[(size_t)r * DIM_ + d] = o;
        if (outb) outb[(size_t)r * DIM_ + d] = (bf16)o;
    }
}

// ---------------- big MFMA GEMM: C = A[M,K] @ BT[N,K]^T (+bias) --------------
// requires M%128==0, N%128==0, K%32==0. 256 thr = 4 waves, each 64x64.
template<bool OUT_BF16>
__global__ __launch_bounds__(256)
void gemm_bt_big(const bf16* __restrict__ A, const bf16* __restrict__ BT,
                 void* __restrict__ Cout, const float* __restrict__ bias,
                 int M, int N, int K) {
    __shared__ bf16 Asm[128 * 32];
    __shared__ bf16 Bsm[128 * 32];
    const int tid = threadIdx.x;
    const int wave = tid >> 6, lane = tid & 63;
    const int m0 = blockIdx.y * 128, n0 = blockIdx.x * 128;
    const int r16 = lane >> 2;
    const int kc  = (lane & 3) * 8;
    const bf16* Ag0 = A  + (size_t)(m0 + wave * 16 + r16) * K + kc;
    const bf16* Ag1 = Ag0 + (size_t)64 * K;
    const bf16* Bg0 = BT + (size_t)(n0 + wave * 16 + r16) * K + kc;
    const bf16* Bg1 = Bg0 + (size_t)64 * K;
    bf16* Al0 = Asm + wave * 512;
    bf16* Al1 = Asm + 2048 + wave * 512;
    bf16* Bl0 = Bsm + wave * 512;
    bf16* Bl1 = Bsm + 2048 + wave * 512;
    const int qd = lane >> 4, l15 = lane & 15;
    const int wm = (wave >> 1) * 64, wn = (wave & 1) * 64;
    f32x4 acc[4][4] = {};
    for (int k0 = 0; k0 < K; k0 += 32) {
        gld_lds16(Ag0 + k0, Al0);
        gld_lds16(Ag1 + k0, Al1);
        gld_lds16(Bg0 + k0, Bl0);
        gld_lds16(Bg1 + k0, Bl1);
        __syncthreads();
        bfv8 af[4], bfr[4];
        #pragma unroll
        for (int i = 0; i < 4; i++)
            af[i] = *(const bfv8*)(Asm + (wm + i * 16 + l15) * 32 + qd * 8);
        #pragma unroll
        for (int j = 0; j < 4; j++)
            bfr[j] = *(const bfv8*)(Bsm + (wn + j * 16 + l15) * 32 + qd * 8);
        #pragma unroll
        for (int i = 0; i < 4; i++)
            #pragma unroll
            for (int j = 0; j < 4; j++)
                acc[i][j] = mfma16(af[i], bfr[j], acc[i][j]);
        __syncthreads();
    }
    float* Cf = (float*)Cout;
    bf16*  Cb = (bf16*)Cout;
    #pragma unroll
    for (int i = 0; i < 4; i++) {
        int rowb = m0 + wm + i * 16 + qd * 4;
        #pragma unroll
        for (int j = 0; j < 4; j++) {
            int col = n0 + wn + j * 16 + l15;
            float bv = bias ? bias[col] : 0.0f;
            #pragma unroll
            for (int r = 0; r < 4; r++) {
                float v = acc[i][j][r] + bv;
                if (OUT_BF16) Cb[(size_t)(rowb + r) * N + col] = (bf16)v;
                else          Cf[(size_t)(rowb + r) * N + col] = v;
            }
        }
    }
}

// ---------------- small MFMA GEMM: 64x64 tile, 2-level batch, tail-safe ------
// z = blockIdx.z; z1 = z/zdiv, z2 = z%zdiv; ptr += z1*s?1 + z2*s?2
// C = alpha * A[M,K] @ BT[N,K]^T (+bias[col]) (+resid bf16, pitch ldc)
template<bool VECK, bool OUT_BF16>
__global__ __launch_bounds__(256)
void gemm_bt_small(const bf16* __restrict__ A, long sA1, long sA2, long lda,
                   const bf16* __restrict__ BT, long sB1, long sB2, long ldb,
                   void* __restrict__ Cout, long sC1, long sC2, long ldc,
                   const float* __restrict__ bias,
                   const bf16* __restrict__ resid, long sR1,
                   int M, int N, int K, float alpha, int zdiv) {
    __shared__ bf16 Asm[64 * 32];
    __shared__ bf16 Bsm[64 * 32];
    const int bz = blockIdx.z;
    const int z1 = bz / zdiv, z2 = bz % zdiv;
    A  += (size_t)z1 * sA1 + (size_t)z2 * sA2;
    BT += (size_t)z1 * sB1 + (size_t)z2 * sB2;
    const int tid = threadIdx.x;
    const int wave = tid >> 6, lane = tid & 63;
    const int m0 = blockIdx.y * 64, n0 = blockIdx.x * 64;
    const int srow = tid >> 2;
    const int skc  = (tid & 3) * 8;
    const int qd = lane >> 4, l15 = lane & 15;
    f32x4 acc[4] = {};
    for (int k0 = 0; k0 < K; k0 += 32) {
        {
            bfv8 v = (bfv8)(bf16)0.0f;
            int gm = m0 + srow;
            if (gm < M) {
                if (VECK) {
                    v = *(const bfv8*)(A + (size_t)gm * lda + k0 + skc);
                } else {
                    #pragma unroll
                    for (int e = 0; e < 8; e++) {
                        int k = k0 + skc + e;
                        if (k < K) v[e] = A[(size_t)gm * lda + k];
                    }
                }
            }
            *(bfv8*)(Asm + srow * 32 + skc) = v;
        }
        {
            bfv8 v = (bfv8)(bf16)0.0f;
            int gn = n0 + srow;
            if (gn < N) {
                if (VECK) {
                    v = *(const bfv8*)(BT + (size_t)gn * ldb + k0 + skc);
                } else {
                    #pragma unroll
                    for (int e = 0; e < 8; e++) {
                        int k = k0 + skc + e;
                        if (k < K) v[e] = BT[(size_t)gn * ldb + k];
                    }
                }
            }
            *(bfv8*)(Bsm + srow * 32 + skc) = v;
        }
        __syncthreads();
        bfv8 af = *(const bfv8*)(Asm + (wave * 16 + l15) * 32 + qd * 8);
        #pragma unroll
        for (int j = 0; j < 4; j++) {
            bfv8 bv = *(const bfv8*)(Bsm + (j * 16 + l15) * 32 + qd * 8);
            acc[j] = mfma16(af, bv, acc[j]);
        }
        __syncthreads();
    }
    float* Cf = (float*)Cout + (size_t)z1 * sC1 + (size_t)z2 * sC2;
    bf16*  Cb = (bf16*)Cout + (size_t)z1 * sC1 + (size_t)z2 * sC2;
    const bf16* rs = resid ? resid + (size_t)z1 * sR1 : nullptr;
    #pragma unroll
    for (int j = 0; j < 4; j++) {
        int col = n0 + j * 16 + l15;
        if (col >= N) continue;
        float bv = bias ? bias[col] : 0.f;
        #pragma unroll
        for (int r = 0; r < 4; r++) {
            int row = m0 + wave * 16 + qd * 4 + r;
            if (row >= M) continue;
            float v = alpha * acc[j][r] + bv;
            if (rs) v += (float)rs[(size_t)row * ldc + col];
            if (OUT_BF16) Cb[(size_t)row * ldc + col] = (bf16)v;
            else          Cf[(size_t)row * ldc + col] = v;
        }
    }
}

// ------- softmax over rows of 196: fp32 in -> bf16 PADDED out [b][224][224] --
__global__ void softmax196(const float* __restrict__ S, bf16* __restrict__ Apad) {
    __shared__ float red[4];
    int row = blockIdx.x;             // b*196 + n
    int b = row / NP_, n = row % NP_;
    const float* p = S + (size_t)row * NP_;
    int t = threadIdx.x;
    float v = (t < NP_) ? p[t] : -1e30f;
    float m = v;
    #pragma unroll
    for (int o = 32; o > 0; o >>= 1) m = fmaxf(m, __shfl_down(m, o));
    int lane = t & 63, wid = t >> 6;
    if (lane == 0) red[wid] = m;
    __syncthreads();
    m = fmaxf(fmaxf(red[0], red[1]), fmaxf(red[2], red[3]));
    float e = (t < NP_) ? __expf(v - m) : 0.f;
    float s = e;
    #pragma unroll
    for (int o = 32; o > 0; o >>= 1) s += __shfl_down(s, o);
    __syncthreads();
    if (lane == 0) red[wid] = s;
    __syncthreads();
    s = red[0] + red[1] + red[2] + red[3];
    if (t < NPP_) {
        bf16* op = Apad + ((size_t)b * NPP_ + n) * NPP_;
        op[t] = (bf16)((t < NP_) ? (e / s) : 0.f);
    }
}

// ---------------- transpose+convert fp32 [R,C] -> bf16 [C,R] -----------------
__global__ void transpose_conv(const float* __restrict__ in, bf16* __restrict__ out,
                               int R, int Cc) {
    __shared__ float t[32][33];
    int c0 = blockIdx.x * 32, r0 = blockIdx.y * 32;
    int tx = threadIdx.x & 31, ty = threadIdx.x >> 5;   // 32 x 8
    #pragma unroll
    for (int i = 0; i < 4; i++) {
        int r = r0 + ty + i * 8;
        if (r < R && c0 + tx < Cc) t[ty + i * 8][tx] = in[(size_t)r * Cc + c0 + tx];
    }
    __syncthreads();
    #pragma unroll
    for (int i = 0; i < 4; i++) {
        int c = c0 + ty + i * 8, r = r0 + tx;
        if (c < Cc && r < R) out[(size_t)c * R + r] = (bf16)t[tx][ty + i * 8];
    }
}

// ---------------- mean-pool over 196 patches: fp32 in -> bf16 out ------------
__global__ void pool_mean(const float* __restrict__ x, bf16* __restrict__ pooled) {
    int b = blockIdx.x;
    int d = blockIdx.y * 256 + threadIdx.x;
    const float* p = x + (size_t)b * NP_ * DIM_ + d;
    float s = 0.f;
    for (int n = 0; n < NP_; n++) s += p[(size_t)n * DIM_];
    pooled[(size_t)b * DIM_ + d] = (bf16)(s * (1.0f / NP_));
}

// =============================================================================
extern "C" void kernel_launch(void* const* d_in, const int* in_sizes, int n_in,
                              void* d_out, int out_size, void* d_ws, size_t ws_size,
                              hipStream_t stream) {
    const float* image  = (const float*)d_in[0];
    const float* pos    = (const float*)d_in[1];
    const float* ln_p_g = (const float*)d_in[2];
    const float* ln_p_b = (const float*)d_in[3];
    const float* W_emb  = (const float*)d_in[4];
    const float* b_emb  = (const float*)d_in[5];
    const float* ln_e_g = (const float*)d_in[6];
    const float* ln_e_b = (const float*)d_in[7];
    const float* WV     = (const float*)d_in[8];
    const float* WK     = (const float*)d_in[9];
    const float* WQ     = (const float*)d_in[10];
    const float* ln_g   = (const float*)d_in[11];
    const float* ln_b   = (const float*)d_in[12];
    const float* W_last = (const float*)d_in[13];
    const float* b_last = (const float*)d_in[14];
    float* out = (float*)d_out;

    char* p = (char*)d_ws;
    auto alloc = [&](size_t bytes) { char* r = p; p += (bytes + 255) & ~(size_t)255; return r; };
    float* x   = (float*)alloc((size_t)ROWS_ * DIM_ * 4);   // 51.38 MB fp32 stream
    // region (51.38 MB): stem hf (fp32, consumed before layers) overlays
    // {S | A_pad | fwT} which are live only inside the layer loop.
    char*  region = alloc((size_t)ROWS_ * DIM_ * 4);
    float* hf    = (float*)region;
    float* S     = (float*)region;                              // 9,834,496 B
    bf16*  A_pad = (bf16*)(region + 9834496);                   // 6,422,528 B
    bf16*  fwT   = (bf16*)(region + 9834496 + 6422528);         // 29,360,128 B
    bf16*  h_bf  = (bf16*)alloc((size_t)ROWS_ * DIM_ * 2);
    // qk: fused [12544, 2048] (q = cols 0..1023, k = cols 1024..2047);
    // also reused as the patchify output buffer [12544, 768] in the stem.
    bf16*  qk_bf = (bf16*)alloc((size_t)ROWS_ * QKD_ * 2);
    bf16*  WembT  = (bf16*)alloc((size_t)DIM_ * PD_ * 2);
    bf16*  WQKT   = (bf16*)alloc((size_t)QKD_ * DIM_ * 2);     // WQ^T rows 0..1023, WK^T rows 1024..2047
    bf16*  WVT    = (bf16*)alloc((size_t)VDIM_ * VDIM_ * 2);
    bf16*  WlastT = (bf16*)alloc((size_t)NC_ * DIM_ * 2);
    bf16*  pooled = (bf16*)alloc((size_t)B_ * DIM_ * 2);

    // --- weight prep (transpose + fp32->bf16), once per call -----------------
    transpose_conv<<<dim3(32, 24), 256, 0, stream>>>(W_emb,  WembT,  PD_,  DIM_);
    transpose_conv<<<dim3(32, 32), 256, 0, stream>>>(WQ,     WQKT,                     DIM_, DIM_);
    transpose_conv<<<dim3(32, 32), 256, 0, stream>>>(WK,     WQKT + (size_t)DIM_ * DIM_, DIM_, DIM_);
    transpose_conv<<<dim3(4, 4),   256, 0, stream>>>(WV,     WVT,    VDIM_, VDIM_);
    transpose_conv<<<dim3(32, 32), 256, 0, stream>>>(W_last, WlastT, DIM_, NC_);

    // --- stem ----------------------------------------------------------------
    patchify_ln<<<ROWS_, 256, 0, stream>>>(image, ln_p_g, ln_p_b, qk_bf);
    gemm_bt_big<false><<<dim3(DIM_ / 128, ROWS_ / 128), 256, 0, stream>>>(
        qk_bf, WembT, hf, b_emb, ROWS_, DIM_, PD_);
    ln_rows<<<ROWS_, 256, 0, stream>>>(hf, nullptr, x, ln_e_g, ln_e_b, pos);

    // --- zero A_pad + fwT (adjacent, 35,782,656 B = 2,236,416 float4) --------
    zero_f4<<<2048, 256, 0, stream>>>((float4*)A_pad, (size_t)35782656 / 16);

    const long XS   = (long)NP_ * DIM_;     // h per-batch stride
    const long QKS  = (long)NP_ * QKD_;     // qk per-batch stride
    const long AS   = (long)NP_ * NP_;      // S per-batch stride
    const long APS  = (long)NPP_ * NPP_;    // padded A per-batch stride
    const long FTS  = (long)DIM_ * NPP_;    // fwT per-batch stride
    for (int layer = 0; layer < DEPTH_; layer++) {
        // h = LN(x)  (bf16)
        ln_rows<<<ROWS_, 256, 0, stream>>>(x, h_bf, nullptr, ln_g, ln_b, nullptr);
        // qk = h @ [WQ|WK]  — single fused GEMM, N=2048
        gemm_bt_big<true><<<dim3(QKD_ / 128, ROWS_ / 128), 256, 0, stream>>>(
            h_bf, WQKT, qk_bf, nullptr, ROWS_, QKD_, DIM_);
        // S = scale * q @ k^T   (batched over b; q/k strided views into qk)
        gemm_bt_small<true, false><<<dim3(4, 4, B_), 256, 0, stream>>>(
            qk_bf, QKS, 0, QKD_, qk_bf + DIM_, QKS, 0, QKD_, S, AS, 0, NP_,
            nullptr, nullptr, 0, NP_, NP_, DIM_, SCALE_, 1);
        // A_pad = softmax(S), cols zero-padded to 224
        softmax196<<<ROWS_, 256, 0, stream>>>(S, A_pad);
        // fwT[b][hd*128+dv][n] = sum_k WVT[dv][k] * h[b][n][hd*128+k];  z = b*8+hd
        gemm_bt_small<true, true><<<dim3(4, 2, B_ * HEADS_), 256, 0, stream>>>(
            WVT, 0, 0, VDIM_,
            h_bf, XS, VDIM_, DIM_,
            fwT, FTS, (long)VDIM_ * NPP_, NPP_,
            nullptr, nullptr, 0, VDIM_, NP_, VDIM_, 1.0f, HEADS_);
        // x = A_pad @ fwT^T + h   (batched over b; K=224 vectorized)
        gemm_bt_small<true, false><<<dim3(16, 4, B_), 256, 0, stream>>>(
            A_pad, APS, 0, NPP_, fwT, FTS, 0, NPP_, x, XS, 0, DIM_,
            nullptr, h_bf, XS, NP_, DIM_, NPP_, 1.0f, 1);
    }

    pool_mean<<<dim3(B_, 4), 256, 0, stream>>>(x, pooled);
    gemm_bt_small<true, false><<<dim3(16, 1, 1), 256, 0, stream>>>(
        pooled, 0, 0, DIM_, WlastT, 0, 0, DIM_, out, 0, 0, NC_,
        b_last, nullptr, 0, B_, NC_, DIM_, 1.0f, 1);
}